// Round 8
// baseline (56.717 us; speedup 1.0000x reference)
//
#include <hip/hip_runtime.h>

#define NROWS 32768
#define NBLK  2048   // 4 waves/block, 4 rows per wave (pipelined, zero-sync)
#define RPW   4

typedef _Float16 h2 __attribute__((ext_vector_type(2)));

// db8 dec filters, pre-reversed (out[i] = sum_k in[2i+k-14]*F[k]), packed as f16 pairs
#define H2C(a,b) {(_Float16)(a##f), (_Float16)(b##f)}

__device__ __forceinline__ float DOT2(unsigned w, h2 f, float acc) {
#if __has_builtin(__builtin_amdgcn_fdot2)
    return __builtin_amdgcn_fdot2(__builtin_bit_cast(h2, w), f, acc, false);
#else
    h2 v = __builtin_bit_cast(h2, w);
    return fmaf((float)v.y, (float)f.y, fmaf((float)v.x, (float)f.x, acc));
#endif
}

__device__ __forceinline__ unsigned PK(float lo, float hi) {
    return __builtin_bit_cast(unsigned, __builtin_amdgcn_cvt_pkrtz(lo, hi));
}

// One group (4 outputs i=4g..4g+3) of one DWT level, f16-pair layout, pads fused.
// Buffer: pair P[k] at u32 index 8+k; front pads idx 1..7, tail mirror pads after data.
// Window: w[m] = P[4g-8+m], m=0..11; out j uses w[j+1+c], c=0..7.
// Same-wave DS ops execute in order -> no lgkm drains needed anywhere.
template<int M, bool STORE>
__device__ __forceinline__ float level_group(const unsigned* __restrict__ inb,
                                             unsigned* __restrict__ outb, int g)
{
    constexpr h2 FA[8] = {
        H2C(0.05441584224308161, 0.3128715909144659),
        H2C(0.6756307362980128, 0.5853546836548691),
        H2C(-0.015829105256023893, -0.2840155429624281),
        H2C(0.00047248457399797254, 0.128747426620186),
        H2C(-0.01736930100202211, -0.04408825393106472),
        H2C(0.013981027917015516, 0.008746094047015655),
        H2C(-0.00487035299301066, -0.0003917403729959771),
        H2C(0.0006754494059985568, -0.00011747678400228192)
    };
    constexpr h2 FD[8] = {
        H2C(-0.00011747678400228192, -0.0006754494059985568),
        H2C(-0.0003917403729959771, 0.00487035299301066),
        H2C(0.008746094047015655, -0.013981027917015516),
        H2C(-0.04408825393106472, 0.01736930100202211),
        H2C(0.128747426620186, -0.00047248457399797254),
        H2C(-0.2840155429624281, 0.015829105256023893),
        H2C(0.5853546836548691, -0.6756307362980128),
        H2C(0.3128715909144659, -0.05441584224308161)
    };
    const uint4 q0 = *(const uint4*)(inb + 4 * g);
    const uint4 q1 = *(const uint4*)(inb + 4 * g + 4);
    const uint4 q2 = *(const uint4*)(inb + 4 * g + 8);
    const unsigned w[12] = {q0.x,q0.y,q0.z,q0.w, q1.x,q1.y,q1.z,q1.w, q2.x,q2.y,q2.z,q2.w};

    float aj[4] = {0.f,0.f,0.f,0.f}, dj[4] = {0.f,0.f,0.f,0.f};
#pragma unroll
    for (int c = 0; c < 8; ++c) {
#pragma unroll
        for (int j = 0; j < 4; ++j) {
            aj[j] = DOT2(w[j+1+c], FA[c], aj[j]);
            dj[j] = DOT2(w[j+1+c], FD[c], dj[j]);
        }
    }
    const int i0 = 4 * g;
    float ds = dj[0] * dj[0];                 // i0 < M always
    if (i0 + 1 < M) ds += dj[1] * dj[1];
    if (i0 + 2 < M) ds += dj[2] * dj[2];
    if (i0 + 3 < M) ds += dj[3] * dj[3];
    if (STORE) {
        constexpr int q = (M - 1) / 2;        // M odd; M == 4*lastg + 3
        if (i0 + 3 < M) {
            *(uint2*)(outb + 8 + 2 * g) = make_uint2(PK(aj[0], aj[1]), PK(aj[2], aj[3]));
        } else if (i0 + 3 == M) {             // last group: outputs i0..i0+2 valid; pair q dups
            *(uint2*)(outb + 8 + 2 * g) = make_uint2(PK(aj[0], aj[1]), PK(aj[2], aj[2]));
        }
        // front mirrors: pair p (p<=6) also stored swapped at idx 7-p
        if (g <= 3) outb[7 - 2 * g] = PK(aj[1], aj[0]);           // p0 = 2g
        if (g <= 2) outb[6 - 2 * g] = PK(aj[3], aj[2]);           // p1 = 2g+1
        // tail mirrors: pair p in [q-7, q-1] also stored swapped at idx 8+2q-p
        const int p0 = 2 * g, p1 = 2 * g + 1;
        if ((unsigned)(p0 - (q - 7)) <= 6u) outb[8 + 2 * q - p0] = PK(aj[1], aj[0]);
        if ((unsigned)(p1 - (q - 7)) <= 6u) outb[8 + 2 * q - p1] = PK(aj[3], aj[2]);
    }
    return ds;
}

// spectral for one row held in registers: sd_i = x[i]-2x[i+1]+x[i+2], i<=1021 (f32 exact)
__device__ __forceinline__ float spectral_row(const float4* xc, int lane) {
    float s = 0.f;
#pragma unroll
    for (int c = 0; c < 4; ++c) {
        const float4 xv = xc[c];
        float n0 = __shfl_down(xv.x, 1, 64);
        float n1 = __shfl_down(xv.y, 1, 64);
        if (c < 3) {
            const float b0 = __shfl(xc[c + 1].x, 0, 64);
            const float b1 = __shfl(xc[c + 1].y, 0, 64);
            if (lane == 63) { n0 = b0; n1 = b1; }
        }
        const float sd0 = xv.x - 2.f * xv.y + xv.z;
        const float sd1 = xv.y - 2.f * xv.z + xv.w;
        s += sd0 * sd0 + sd1 * sd1;
        const float sd2 = xv.z - 2.f * xv.w + n0;
        const float sd3 = xv.w - 2.f * n0 + n1;
        if (c < 3 || lane < 63)
            s += sd2 * sd2 + sd3 * sd3;
    }
    return s;
}

__global__ __launch_bounds__(256) void combined_loss_kernel(
    const float* __restrict__ x, const float* __restrict__ y,
    float* __restrict__ partials)
{
    // per-wave u32 pair buffers: B0[528] B1[276] B2[152] = 956 u32 = 3824 B/wave
    __shared__ __align__(16) unsigned lds[4][956];
    __shared__ float wsum[4];

    const int tid  = threadIdx.x;
    const int wid  = tid >> 6;
    const int lane = tid & 63;
    unsigned* const W  = lds[wid];
    unsigned* const B0 = W;          // L=1024: 8 front + 512 data + 7 tail
    unsigned* const B1 = W + 528;    // M=519:  8 + 260 + mirrors (reads to idx 275)
    unsigned* const B2 = W + 804;    // M=267:  8 + 134 + mirrors (reads to idx 151)

    const int rbase = (blockIdx.x * 4 + wid) * RPW;
    const float4* xp = (const float4*)x + (size_t)rbase * 256;
    const float4* yp = (const float4*)y + (size_t)rbase * 256;

    float4 xc[4], yc[4];
#pragma unroll
    for (int c = 0; c < 4; ++c) {
        xc[c] = xp[c * 64 + lane];
        yc[c] = yp[c * 64 + lane];
    }

    float s_mse = 0.f, s_spec = 0.f, s_d1 = 0.f, s_d2 = 0.f, s_d3 = 0.f;

#pragma unroll 1
    for (int k = 0; k < RPW; ++k) {
        // stage current row with fused mirror pads (consumes yc; xc kept for spectral)
#pragma unroll
        for (int c = 0; c < 4; ++c) {
            const int u = c * 64 + lane;
            const float4 e = make_float4(xc[c].x - yc[c].x, xc[c].y - yc[c].y,
                                         xc[c].z - yc[c].z, xc[c].w - yc[c].w);
            s_mse += e.x * e.x + e.y * e.y + e.z * e.z + e.w * e.w;
            *(uint2*)(B0 + 8 + 2 * u) = make_uint2(PK(e.x, e.y), PK(e.z, e.w));
            if (c == 0 && lane <= 3) {           // front pads (reflection of e[0..13])
                B0[7 - 2 * lane] = PK(e.y, e.x);
                if (lane <= 2) B0[6 - 2 * lane] = PK(e.w, e.z);
            }
            if (c == 3 && lane >= 60) {          // tail pads (reflection of e[1009..1023])
                if (lane >= 61) B0[1031 - 2 * u] = PK(e.y, e.x);
                B0[1030 - 2 * u] = PK(e.w, e.z);
            }
        }
        s_spec += spectral_row(xc, lane);

        // prefetch next row; loads stay in flight across all three levels (no vmcnt drains)
        if (k + 1 < RPW) {
            const float4* xpn = xp + (size_t)(k + 1) * 256;
            const float4* ypn = yp + (size_t)(k + 1) * 256;
#pragma unroll
            for (int c = 0; c < 4; ++c) {
                xc[c] = xpn[c * 64 + lane];
                yc[c] = ypn[c * 64 + lane];
            }
        }

        // levels: no explicit sync — same-wave DS ops are in-order; compiler inserts
        // fine-grained lgkmcnt(N) only before VALU consumption of ds_read results
        for (int g = lane; g < 130; g += 64) s_d1 += level_group<519, true>(B0, B1, g);
        for (int g = lane; g < 67;  g += 64) s_d2 += level_group<267, true>(B1, B2, g);
        if (lane < 36)                       s_d3 += level_group<141, false>(B2, B2, lane);
    }

    const float wm  = 1.0f / 33554432.0f;             // 32*1024*1024
    const float wsp = 1.0f / 33488896.0f;             // 32*1024*1022
    const float w1  = 1.0f / (3.0f * 17006592.0f);    // 32768*519
    const float w2  = 1.0f / (3.0f * 8749056.0f);     // 32768*267
    const float w3  = 1.0f / (3.0f * 4620288.0f);     // 32768*141
    float local = wm * s_mse + wsp * s_spec + w1 * s_d1 + w2 * s_d2 + w3 * s_d3;

#pragma unroll
    for (int off = 32; off > 0; off >>= 1)
        local += __shfl_down(local, off, 64);
    if (lane == 0) wsum[wid] = local;
    __syncthreads();
    if (tid == 0) partials[blockIdx.x] = wsum[0] + wsum[1] + wsum[2] + wsum[3];
}

__global__ __launch_bounds__(256) void reduce_kernel(const float* __restrict__ partials,
                                                     int n, float* __restrict__ out)
{
    __shared__ double sm[256];
    double s = 0.0;
    for (int i = threadIdx.x; i < n; i += 256) s += (double)partials[i];
    sm[threadIdx.x] = s;
    __syncthreads();
    for (int off = 128; off > 0; off >>= 1) {
        if (threadIdx.x < off) sm[threadIdx.x] += sm[threadIdx.x + off];
        __syncthreads();
    }
    if (threadIdx.x == 0) out[0] = (float)sm[0];
}

extern "C" void kernel_launch(void* const* d_in, const int* in_sizes, int n_in,
                              void* d_out, int out_size, void* d_ws, size_t ws_size,
                              hipStream_t stream) {
    const float* x = (const float*)d_in[0];   // output
    const float* y = (const float*)d_in[1];   // target
    float* partials = (float*)d_ws;           // NBLK floats (8 KB)
    combined_loss_kernel<<<NBLK, 256, 0, stream>>>(x, y, partials);
    reduce_kernel<<<1, 256, 0, stream>>>(partials, NBLK, (float*)d_out);
}